// Round 14
// baseline (200.350 us; speedup 1.0000x reference)
//
#include <hip/hip_runtime.h>

// Wav2Vec2BertSelfAttention on MI355X (gfx950)
// B=4, S=1024, HID=1024, NH=16, HD=64, LEFT=64, RIGHT=8, NUM_POS=73
//
// Round 14: r13 + attn TWO-UNIT interleave. Block = (b,h, 64 q-rows as two
// 32-row units). Sections: ph1 = QK(u1); middle = stores+PV(u1) || QK(u2)
// (raises probs-store duty cycle ~50%->~70%); ph3 = stores+PV(u2).
// K/V tiles shared by both units (same bh). paf1 dies as paf2 is born.
//   Q''[qt][dcg][lq][dc2][8]   K''[kt][half][dcg][p][dc2][8]
//   V''[vt2][db][lq][Qr][8]   (per (b,head) 128KB blocks, dense 1KB loads)

using short8 = __attribute__((ext_vector_type(8))) short;
using f32x4  = __attribute__((ext_vector_type(4))) float;
using fl4    = __attribute__((ext_vector_type(4))) float;
using u16x4  = __attribute__((ext_vector_type(4))) unsigned short;

#define MFMA16(a, b, c) __builtin_amdgcn_mfma_f32_16x16x32_bf16((a), (b), (c), 0, 0, 0)

// 0.125 (1/sqrt(64)) * log2(e)
#define SCL2E 0.18033688011112042f

__device__ __forceinline__ float bf2f(unsigned short u) {
  union { unsigned int i; float f; } c;
  c.i = ((unsigned int)u) << 16;
  return c.f;
}
__device__ __forceinline__ unsigned short f2bf(float f) {
  union { float f; unsigned int i; } c;
  c.f = f;
  unsigned int x = c.i;
  return (unsigned short)((x + 0x7fffu + ((x >> 16) & 1u)) >> 16);  // RNE
}
__device__ __forceinline__ float u2f(unsigned u) {
  union { unsigned i; float f; } c;
  c.i = u;
  return c.f;
}

__device__ __forceinline__ void gload_lds16(const void* g, void* l) {
  __builtin_amdgcn_global_load_lds(
      (const __attribute__((address_space(1))) void*)g,
      (__attribute__((address_space(3))) void*)l, 16, 0, 0);
}

// ---------------------------------------------------------------- convert
__global__ void cvt_f32_bf16(const float* __restrict__ in,
                             unsigned short* __restrict__ out, int n4) {
  int i = blockIdx.x * blockDim.x + threadIdx.x;
  int stride = gridDim.x * blockDim.x;
  for (; i < n4; i += stride) {
    fl4 v = ((const fl4*)in)[i];
    u16x4 o;
    o[0] = f2bf(v[0]); o[1] = f2bf(v[1]); o[2] = f2bf(v[2]); o[3] = f2bf(v[3]);
    ((u16x4*)out)[i] = o;
  }
}

// 4 weight matrices -> bf16 + dist_emb -> padded bf16 [80][64], one launch.
__global__ void cvt_w4d(const float* __restrict__ w0, const float* __restrict__ w1,
                        const float* __restrict__ w2, const float* __restrict__ w3,
                        const float* __restrict__ de,
                        unsigned short* __restrict__ o0, unsigned short* __restrict__ o1,
                        unsigned short* __restrict__ o2, unsigned short* __restrict__ o3,
                        unsigned short* __restrict__ od) {
  if (blockIdx.x == 1024) {
    for (int i = threadIdx.x; i < 80 * 64; i += 256)
      od[i] = (i < 73 * 64) ? f2bf(de[i]) : (unsigned short)0;
    return;
  }
  const int which = blockIdx.x >> 8;
  const float* in = which == 0 ? w0 : which == 1 ? w1 : which == 2 ? w2 : w3;
  unsigned short* out = which == 0 ? o0 : which == 1 ? o1 : which == 2 ? o2 : o3;
  int i = (blockIdx.x & 255) * 256 + threadIdx.x;
#pragma unroll
  for (int it = 0; it < 4; ++it, i += 65536) {
    fl4 v = ((const fl4*)in)[i];
    u16x4 o;
    o[0] = f2bf(v[0]); o[1] = f2bf(v[1]); o[2] = f2bf(v[2]); o[3] = f2bf(v[3]);
    ((u16x4*)out)[i] = o;
  }
}

// ---------------------------------------------------------------- fused QKV GEMM
// r=0 Q = X@Wq^T (+bq), r=1 K = X@Wk^T (+bk), r=2 V = Wv@X^T (+bv, row)
__global__ __launch_bounds__(256)
void gemm_qkv3(const unsigned short* __restrict__ X,
               const unsigned short* __restrict__ Bq,
               const unsigned short* __restrict__ Bk,
               const unsigned short* __restrict__ Bv,
               const float* __restrict__ biq, const float* __restrict__ bik,
               const float* __restrict__ biv,
               unsigned short* __restrict__ Cq, unsigned short* __restrict__ Ck,
               unsigned short* __restrict__ Cv) {
  __shared__ unsigned short lA[128 * 32];
  __shared__ unsigned short lB[128 * 32];
  const int i = blockIdx.x;
  const int wgid = (i & 7) * 96 + (i >> 3);   // XCD-chunked (768 % 8 == 0)
  const int r = wgid >> 8;
  const int id = wgid & 255;
  int bm, bn;
  const unsigned short *Aa, *Bb;
  if (r == 2) {
    bm = (id >> 5) * 128; bn = (id & 31) * 128;
    Aa = Bv; Bb = X;
  } else {
    bm = (id >> 3) * 128; bn = (id & 7) * 128;
    Aa = X; Bb = (r == 0) ? Bq : Bk;
  }
  const float* bias = (r == 0) ? biq : (r == 1) ? bik : biv;

  const int tid = threadIdx.x;
  const int wave = tid >> 6, lane = tid & 63;
  const int wm = wave >> 1, wn = wave & 1;

  f32x4 acc[4][4];
#pragma unroll
  for (int m = 0; m < 4; ++m)
#pragma unroll
    for (int n = 0; n < 4; ++n) acc[m][n] = (f32x4){0.f, 0.f, 0.f, 0.f};

  const int t0 = tid, t1 = tid + 256;
  const int ar0 = t0 >> 2, ak0 = (t0 & 3) * 8;
  const int ar1 = t1 >> 2, ak1 = (t1 & 3) * 8;
  const unsigned short* Ab = Aa + (size_t)bm * 1024;
  const unsigned short* Bbb = Bb + (size_t)bn * 1024;
  const int fr = lane & 15, fk = (lane >> 4) * 8;

  for (int kt = 0; kt < 1024; kt += 32) {
    gload_lds16(Ab + (size_t)ar0 * 1024 + kt + ak0, (void*)&lA[(wave * 64) * 8]);
    gload_lds16(Ab + (size_t)ar1 * 1024 + kt + ak1, (void*)&lA[2048 + (wave * 64) * 8]);
    gload_lds16(Bbb + (size_t)ar0 * 1024 + kt + ak0, (void*)&lB[(wave * 64) * 8]);
    gload_lds16(Bbb + (size_t)ar1 * 1024 + kt + ak1, (void*)&lB[2048 + (wave * 64) * 8]);
    __syncthreads();
    short8 af[4], bf[4];
#pragma unroll
    for (int m = 0; m < 4; ++m)
      af[m] = *(const short8*)&lA[(wm * 64 + m * 16 + fr) * 32 + fk];
#pragma unroll
    for (int n = 0; n < 4; ++n)
      bf[n] = *(const short8*)&lB[(wn * 64 + n * 16 + fr) * 32 + fk];
#pragma unroll
    for (int m = 0; m < 4; ++m)
#pragma unroll
      for (int n = 0; n < 4; ++n) acc[m][n] = MFMA16(af[m], bf[n], acc[m][n]);
    __syncthreads();
  }

  const int cr = (lane >> 4) * 4, cc = lane & 15;
#pragma unroll
  for (int m = 0; m < 4; ++m)
#pragma unroll
    for (int n = 0; n < 4; ++n) {
      const int col = bn + wn * 64 + n * 16 + cc;
#pragma unroll
      for (int g = 0; g < 4; ++g) {
        const int row = bm + wm * 64 + m * 16 + cr + g;
        if (r == 2) {
          const float v = acc[m][n][g] + bias[row];
          const int head = row >> 6, d = row & 63;
          const int b2 = col >> 10, sl = col & 1023, kk = sl & 31;
          size_t idx = ((size_t)((b2 << 4) + head) << 16) +
                       (size_t)(((sl >> 5) * 4 + (d >> 4)) * 512) +
                       (d & 15) * 32 + ((kk >> 3) * 8) + (kk & 7);
          Cv[idx] = f2bf(v);
        } else {
          const float v = acc[m][n][g] + bias[col];
          const int head = col >> 6, d = col & 63;
          const int b2 = row >> 10, sl = row & 1023;
          const int dc = d >> 3;
          const size_t hb = (size_t)((b2 << 4) + head) << 16;
          if (r == 0) {
            size_t idx = hb +
                         (size_t)((((sl >> 4) * 2 + (dc >> 2)) * 16 + (sl & 15)) * 32) +
                         (dc & 3) * 8 + (d & 7);
            Cq[idx] = f2bf(v);
          } else {
            const int kt2 = sl >> 5;
            const int p = ((sl >> 3) & 3) * 4 + (sl & 3);
            const int half = (sl >> 2) & 1;
            size_t idx = hb +
                         (size_t)((((kt2 * 2 + half) * 2 + (dc >> 2)) * 512)) +
                         p * 32 + (dc & 3) * 8 + (d & 7);
            Ck[idx] = f2bf(v);
          }
        }
      }
    }
}

// ---------------------------------------------------------------- GEMM f32 out
__global__ __launch_bounds__(256)
void gemm_nt_f32(const unsigned short* __restrict__ A,
                 const unsigned short* __restrict__ B,
                 const float* __restrict__ bias, float* __restrict__ Cp) {
  __shared__ unsigned short lA[128 * 32];
  __shared__ unsigned short lB[128 * 32];
  const int tid = threadIdx.x;
  const int wave = tid >> 6, lane = tid & 63;
  const int wm = wave >> 1, wn = wave & 1;
  const int bm = blockIdx.x * 128, bn = blockIdx.y * 128;

  f32x4 acc[4][4];
#pragma unroll
  for (int m = 0; m < 4; ++m)
#pragma unroll
    for (int n = 0; n < 4; ++n) acc[m][n] = (f32x4){0.f, 0.f, 0.f, 0.f};

  const int t0 = tid, t1 = tid + 256;
  const int ar0 = t0 >> 2, ak0 = (t0 & 3) * 8;
  const int ar1 = t1 >> 2, ak1 = (t1 & 3) * 8;
  const unsigned short* Ab = A + (size_t)bm * 1024;
  const unsigned short* Bb = B + (size_t)bn * 1024;
  const int fr = lane & 15, fk = (lane >> 4) * 8;

  for (int kt = 0; kt < 1024; kt += 32) {
    gload_lds16(Ab + (size_t)ar0 * 1024 + kt + ak0, (void*)&lA[(wave * 64) * 8]);
    gload_lds16(Ab + (size_t)ar1 * 1024 + kt + ak1, (void*)&lA[2048 + (wave * 64) * 8]);
    gload_lds16(Bb + (size_t)ar0 * 1024 + kt + ak0, (void*)&lB[(wave * 64) * 8]);
    gload_lds16(Bb + (size_t)ar1 * 1024 + kt + ak1, (void*)&lB[2048 + (wave * 64) * 8]);
    __syncthreads();
    short8 af[4], bf[4];
#pragma unroll
    for (int m = 0; m < 4; ++m)
      af[m] = *(const short8*)&lA[(wm * 64 + m * 16 + fr) * 32 + fk];
#pragma unroll
    for (int n = 0; n < 4; ++n)
      bf[n] = *(const short8*)&lB[(wn * 64 + n * 16 + fr) * 32 + fk];
#pragma unroll
    for (int m = 0; m < 4; ++m)
#pragma unroll
      for (int n = 0; n < 4; ++n) acc[m][n] = MFMA16(af[m], bf[n], acc[m][n]);
    __syncthreads();
  }

  const int cr = (lane >> 4) * 4, cc = lane & 15;
#pragma unroll
  for (int m = 0; m < 4; ++m)
#pragma unroll
    for (int n = 0; n < 4; ++n) {
      const int col = bn + wn * 64 + n * 16 + cc;
#pragma unroll
      for (int g = 0; g < 4; ++g) {
        const int row = bm + wm * 64 + m * 16 + cr + g;
        Cp[(size_t)row * 1024 + col] = acc[m][n][g] + bias[col];
      }
    }
}

// ---------------------------------------------------------------- attention
// Block = (b,h, 64 q-rows = units 1,2 of 32 rows; each unit = groups A,B).
// 4 waves split k (256 cols each). ph1: QK(u1). middle: PV+stores(u1) || QK(u2).
// ph3: PV+stores(u2). 5 barriers. K/V tiles shared across units (same bh).
__global__ __launch_bounds__(256, 2)
void attn_kernel(const unsigned short* __restrict__ q,
                 const unsigned short* __restrict__ k,
                 const unsigned short* __restrict__ vt,
                 const unsigned short* __restrict__ demb_bf,
                 float* __restrict__ probs,
                 unsigned short* __restrict__ ctx) {
  const int i = blockIdx.x;
  const int x = i & 7, s = i >> 3;            // 1024 blocks, 1024%8==0
  const int bh = ((s >> 4) << 3) + x;         // 16 same-XCD blocks share bh
  const int j = s & 15;                       // 64-row slab index
  const int hd = bh & 15, b = bh >> 4;
  const int tid = threadIdx.x, w = tid >> 6, lane = tid & 63;
  const int lq = lane & 15, Qr = lane >> 4;
  const int qA1 = j * 64, qB1 = qA1 + 16, qA2 = qA1 + 32, qB2 = qA1 + 48;

  __shared__ unsigned short qdc[2][32][78];  // 9.75 KB, PRE-SCALED by SCL2E
  __shared__ float reds[2][4][32];           // 1 KB
  __shared__ float red[4][4][32][16];        // 32 KB partial PV (reused u1->u2)

  const size_t hb = (size_t)((b << 4) + hd) << 16;
  const int lo16 = lq * 32 + Qr * 8;

  // Q frags: unit1 at qseg 2j (offset j*8*512), unit2 at +2048
  const unsigned short* qh1 = q + hb + (size_t)(j * 8) * 512;
  const unsigned short* qh2 = qh1 + 2048;
  short8 q1A0 = *(const short8*)(qh1 + lo16);
  short8 q1A1 = *(const short8*)(qh1 + 512 + lo16);
  short8 q1B0 = *(const short8*)(qh1 + 1024 + lo16);
  short8 q1B1 = *(const short8*)(qh1 + 1536 + lo16);
  short8 q2A0 = *(const short8*)(qh2 + lo16);
  short8 q2A1 = *(const short8*)(qh2 + 512 + lo16);
  short8 q2B0 = *(const short8*)(qh2 + 1024 + lo16);
  short8 q2B1 = *(const short8*)(qh2 + 1536 + lo16);

  // qd for both units (20 p-groups over 4 waves)
  for (int pgq = w; pgq < 20; pgq += 4) {
    const int u = pgq >= 10;
    const int pp = pgq - u * 10;
    const int qblk = pp >= 5;
    const int pg = pp - qblk * 5;
    const unsigned short* dp = demb_bf + (size_t)(pg * 16 + lq) * 64 + Qr * 8;
    short8 a0 = *(const short8*)dp;
    short8 a1 = *(const short8*)(dp + 32);
    short8 f0 = u ? (qblk ? q2B0 : q2A0) : (qblk ? q1B0 : q1A0);
    short8 f1 = u ? (qblk ? q2B1 : q2A1) : (qblk ? q1B1 : q1A1);
    f32x4 c = (f32x4){0.f, 0.f, 0.f, 0.f};
    c = MFMA16(a0, f0, c);
    c = MFMA16(a1, f1, c);
#pragma unroll
    for (int g = 0; g < 4; ++g) {
      const int p = pg * 16 + Qr * 4 + g;
      if (p < 73) qdc[u][qblk * 16 + lq][p] = f2bf(c[g] * SCL2E);
    }
  }
  __syncthreads();  // B1: qdc ready

  const float qd0A1 = bf2f(qdc[0][lq][0]),      qd72A1 = bf2f(qdc[0][lq][72]);
  const float qd0B1 = bf2f(qdc[0][16 + lq][0]), qd72B1 = bf2f(qdc[0][16 + lq][72]);
  const float qd0A2 = bf2f(qdc[1][lq][0]),      qd72A2 = bf2f(qdc[1][lq][72]);
  const float qd0B2 = bf2f(qdc[1][16 + lq][0]), qd72B2 = bf2f(qdc[1][16 + lq][72]);

  const unsigned short* kh = k + hb + (size_t)(w * 8) * 2048 + lo16;
  const unsigned short* vh = vt + hb + (size_t)(w * 8) * 2048 + lo16;

  // exp helper as macro over (se,so, qA,qB base, qd scalars, qdc unit, paf, ssum)
#define QKEXP(se, so, qAx, qd0x, qd72x, UU, LQOFF, paf, ssum, tglob)          \
  {                                                                           \
    float pe[4], po[4];                                                       \
    if ((tglob)*32 + 31 < (qAx)-64) {                                         \
      _Pragma("unroll") for (int g = 0; g < 4; ++g) {                         \
        pe[g] = exp2f(fmaf(se[g], SCL2E, qd0x));                              \
        po[g] = exp2f(fmaf(so[g], SCL2E, qd0x));                              \
      }                                                                       \
    } else if ((tglob)*32 > (qAx) + 23) {                                     \
      _Pragma("unroll") for (int g = 0; g < 4; ++g) {                         \
        pe[g] = exp2f(fmaf(se[g], SCL2E, qd72x));                             \
        po[g] = exp2f(fmaf(so[g], SCL2E, qd72x));                             \
      }                                                                       \
    } else {                                                                  \
      const int c0 = (tglob)*32 + Qr * 8 - ((qAx) + lq);                      \
      _Pragma("unroll") for (int g = 0; g < 4; ++g) {                         \
        int d0 = c0 + g;     d0 = d0 < -64 ? -64 : (d0 > 8 ? 8 : d0);         \
        int d1 = c0 + 4 + g; d1 = d1 < -64 ? -64 : (d1 > 8 ? 8 : d1);         \
        pe[g] = exp2f(fmaf(se[g], SCL2E, bf2f(qdc[UU][(LQOFF) + lq][d0 + 64])));\
        po[g] = exp2f(fmaf(so[g], SCL2E, bf2f(qdc[UU][(LQOFF) + lq][d1 + 64])));\
      }                                                                       \
    }                                                                         \
    _Pragma("unroll") for (int g = 0; g < 4; ++g) ssum += pe[g] + po[g];      \
    asm("v_cvt_pk_bf16_f32 %0, %1, %2" : "=v"(paf[0]) : "v"(pe[0]), "v"(pe[1]));\
    asm("v_cvt_pk_bf16_f32 %0, %1, %2" : "=v"(paf[1]) : "v"(pe[2]), "v"(pe[3]));\
    asm("v_cvt_pk_bf16_f32 %0, %1, %2" : "=v"(paf[2]) : "v"(po[0]), "v"(po[1]));\
    asm("v_cvt_pk_bf16_f32 %0, %1, %2" : "=v"(paf[3]) : "v"(po[2]), "v"(po[3]));\
  }

#define STORE8(paf, inv, prow, t)                                             \
  {                                                                           \
    f32x4 p0, p1;                                                             \
    p0[0] = u2f(paf[0] << 16) * inv;                                          \
    p0[1] = u2f(paf[0] & 0xffff0000u) * inv;                                  \
    p0[2] = u2f(paf[1] << 16) * inv;                                          \
    p0[3] = u2f(paf[1] & 0xffff0000u) * inv;                                  \
    p1[0] = u2f(paf[2] << 16) * inv;                                          \
    p1[1] = u2f(paf[2] & 0xffff0000u) * inv;                                  \
    p1[2] = u2f(paf[3] << 16) * inv;                                          \
    p1[3] = u2f(paf[3] & 0xffff0000u) * inv;                                  \
    *(f32x4*)&prow[(t)*32] = p0;                                              \
    *(f32x4*)&prow[(t)*32 + 4] = p1;                                          \
  }

#define PACK8(paf) ({ union { unsigned uu4[4]; short8 s8v; } _u;              \
    _u.uu4[0] = paf[0]; _u.uu4[1] = paf[1];                                   \
    _u.uu4[2] = paf[2]; _u.uu4[3] = paf[3]; _u.s8v; })

  // -------- ph1: QK(u1) over 8 tiles
  float sA1 = 0.f, sB1 = 0.f;
  unsigned paf1A[8][4], paf1B[8][4];
#pragma unroll
  for (int t = 0; t < 8; ++t) {
    const unsigned short* kp = kh + t * 2048;
    short8 ae0 = *(const short8*)kp;
    short8 ae1 = *(const short8*)(kp + 512);
    short8 ao0 = *(const short8*)(kp + 1024);
    short8 ao1 = *(const short8*)(kp + 1536);
    f32x4 se = (f32x4){0.f, 0.f, 0.f, 0.f}, so = se, se2 = se, so2 = se;
    se = MFMA16(ae0, q1A0, se);  se = MFMA16(ae1, q1A1, se);
    so = MFMA16(ao0, q1A0, so);  so = MFMA16(ao1, q1A1, so);
    se2 = MFMA16(ae0, q1B0, se2); se2 = MFMA16(ae1, q1B1, se2);
    so2 = MFMA16(ao0, q1B0, so2); so2 = MFMA16(ao1, q1B1, so2);
    const int tg = w * 8 + t;
    QKEXP(se, so, qA1, qd0A1, qd72A1, 0, 0, paf1A[t], sA1, tg);
    QKEXP(se2, so2, qB1, qd0B1, qd72B1, 0, 16, paf1B[t], sB1, tg);
  }
  sA1 += __shfl_xor(sA1, 16, 64); sA1 += __shfl_xor(sA1, 32, 64);
  sB1 += __shfl_xor(sB1, 16, 64); sB1 += __shfl_xor(sB1, 32, 64);
  if (lane < 16) { reds[0][w][lane] = sA1; reds[0][w][16 + lane] = sB1; }
  __syncthreads();  // B2: reds(u1) ready

  const float invA1 = 1.0f / (reds[0][0][lq] + reds[0][1][lq] +
                              reds[0][2][lq] + reds[0][3][lq]);
  const float invB1 = 1.0f / (reds[0][0][16 + lq] + reds[0][1][16 + lq] +
                              reds[0][2][16 + lq] + reds[0][3][16 + lq]);
  float* prowA1 = probs + ((size_t)bh * 1024 + qA1 + lq) * 1024 + w * 256 + Qr * 8;
  float* prowB1 = prowA1 + (size_t)16 * 1024;

  // -------- middle: PV+stores(u1) interleaved with QK(u2)
  float sA2 = 0.f, sB2 = 0.f;
  unsigned paf2A[8][4], paf2B[8][4];
  f32x4 o1A0 = (f32x4){0.f, 0.f, 0.f, 0.f}, o1A1 = o1A0, o1A2 = o1A0, o1A3 = o1A0;
  f32x4 o1B0 = o1A0, o1B1 = o1A0, o1B2 = o1A0, o1B3 = o1A0;
#pragma unroll
  for (int t = 0; t < 8; ++t) {
    const unsigned short* vp = vh + t * 2048;
    short8 v0 = *(const short8*)vp;
    short8 v1 = *(const short8*)(vp + 512);
    short8 v2 = *(const short8*)(vp + 1024);
    short8 v3 = *(const short8*)(vp + 1536);
    const unsigned short* kp = kh + t * 2048;
    short8 ae0 = *(const short8*)kp;
    short8 ae1 = *(const short8*)(kp + 512);
    short8 ao0 = *(const short8*)(kp + 1024);
    short8 ao1 = *(const short8*)(kp + 1536);

    // PV u1
    const short8 pa = PACK8(paf1A[t]);
    const short8 pb = PACK8(paf1B[t]);
    o1A0 = MFMA16(pa, v0, o1A0); o1A1 = MFMA16(pa, v1, o1A1);
    o1A2 = MFMA16(pa, v2, o1A2); o1A3 = MFMA16(pa, v3, o1A3);
    o1B0 = MFMA16(pb, v0, o1B0); o1B1 = MFMA16(pb, v1, o1B1);
    o1B2 = MFMA16(pb, v2, o1B2); o1B3 = MFMA16(pb, v3, o1B3);
    // stores u1
    STORE8(paf1A[t], invA1, prowA1, t);
    STORE8(paf1B[t], invB1, prowB1, t);
    // QK u2
    f32x4 se = (f32x4){0.f, 0.f, 0.f, 0.f}, so = se, se2 = se, so2 = se;
    se = MFMA16(ae0, q2A0, se);  se = MFMA16(ae1, q2A1, se);
    so = MFMA16(ao0, q2A0, so);  so = MFMA16(ao1, q2A1, so);
    se2 = MFMA16(ae0, q2B0, se2); se2 = MFMA16(ae1, q2B1, se2);
    so2 = MFMA16(ao0, q2B0, so2); so2 = MFMA16(ao1, q2B1, so2);
    const int tg = w * 8 + t;
    QKEXP(se, so, qA2, qd0A2, qd72A2, 1, 0, paf2A[t], sA2, tg);
    QKEXP(se2, so2, qB2, qd0B2, qd72B2, 1, 16, paf2B[t], sB2, tg);
  }
  sA2 += __shfl_xor(sA2, 16, 64); sA2 += __shfl_xor(sA2, 32, 64);
  sB2 += __shfl_xor(sB2, 16, 64); sB2 += __shfl_xor(sB2, 32, 64);
  if (lane < 16) { reds[1][w][lane] = sA2; reds[1][w][16 + lane] = sB2; }
  // PV(u1) partials -> red
#pragma unroll
  for (int g = 0; g < 4; ++g) {
    red[w][0][Qr * 4 + g][lq] = o1A0[g];
    red[w][1][Qr * 4 + g][lq] = o1A1[g];
    red[w][2][Qr * 4 + g][lq] = o1A2[g];
    red[w][3][Qr * 4 + g][lq] = o1A3[g];
    red[w][0][16 + Qr * 4 + g][lq] = o1B0[g];
    red[w][1][16 + Qr * 4 + g][lq] = o1B1[g];
    red[w][2][16 + Qr * 4 + g][lq] = o1B2[g];
    red[w][3][16 + Qr * 4 + g][lq] = o1B3[g];
  }
  __syncthreads();  // B3: red(u1) + reds(u2) ready

  // ctx u1
  {
    const int qrow = tid >> 3;
    const int d0 = (tid & 7) * 8;
    const float invq = 1.0f / (reds[0][0][qrow] + reds[0][1][qrow] +
                               reds[0][2][qrow] + reds[0][3][qrow]);
    u16x4 cv0, cv1;
#pragma unroll
    for (int jj = 0; jj < 8; ++jj) {
      const int d = d0 + jj;
      const int db = d >> 4, dd = d & 15;
      float sum = red[0][db][qrow][dd] + red[1][db][qrow][dd] +
                  red[2][db][qrow][dd] + red[3][db][qrow][dd];
      if (jj < 4) cv0[jj] = f2bf(sum * invq);
      else        cv1[jj - 4] = f2bf(sum * invq);
    }
    unsigned short* cb =
        ctx + ((size_t)(b * 1024 + qA1 + qrow)) * 1024 + hd * 64 + d0;
    *(u16x4*)cb = cv0;
    *(u16x4*)(cb + 4) = cv1;
  }
  __syncthreads();  // B4: red free for u2

  // -------- ph3: PV+stores(u2)
  const float invA2 = 1.0f / (reds[1][0][lq] + reds[1][1][lq] +
                              reds[1][2][lq] + reds[1][3][lq]);
  const float invB2 = 1.0f / (reds[1][0][16 + lq] + reds[1][1][16 + lq] +
                              reds[1][2][16 + lq] + reds[1][3][16 + lq]);
  float* prowA2 = probs + ((size_t)bh * 1024 + qA2 + lq) * 1024 + w * 256 + Qr * 8;
  float* prowB2 = prowA2 + (size_t)16 * 1024;

  f32x4 o2A0 = (f32x4){0.f, 0.f, 0.f, 0.f}, o2A1 = o2A0, o2A2 = o2A0, o2A3 = o2A0;
  f32x4 o2B0 = o2A0, o2B1 = o2A0, o2B2 = o2A0, o2B3 = o2A0;
#pragma unroll
  for (int t = 0; t < 8; ++t) {
    const unsigned short* vp = vh + t * 2048;
    short8 v0 = *(const short8*)vp;
    short8 v1 = *(const short8*)(vp + 512);
    short8 v2 = *(const short8*)(vp + 1024);
    short8 v3 = *(const short8*)(vp + 1536);
    const short8 pa = PACK8(paf2A[t]);
    const short8 pb = PACK8(paf2B[t]);
    o2A0 = MFMA16(pa, v0, o2A0); o2A1 = MFMA16(pa, v1, o2A1);
    o2A2 = MFMA16(pa, v2, o2A2); o2A3 = MFMA16(pa, v3, o2A3);
    o2B0 = MFMA16(pb, v0, o2B0); o2B1 = MFMA16(pb, v1, o2B1);
    o2B2 = MFMA16(pb, v2, o2B2); o2B3 = MFMA16(pb, v3, o2B3);
    STORE8(paf2A[t], invA2, prowA2, t);
    STORE8(paf2B[t], invB2, prowB2, t);
  }
#pragma unroll
  for (int g = 0; g < 4; ++g) {
    red[w][0][Qr * 4 + g][lq] = o2A0[g];
    red[w][1][Qr * 4 + g][lq] = o2A1[g];
    red[w][2][Qr * 4 + g][lq] = o2A2[g];
    red[w][3][Qr * 4 + g][lq] = o2A3[g];
    red[w][0][16 + Qr * 4 + g][lq] = o2B0[g];
    red[w][1][16 + Qr * 4 + g][lq] = o2B1[g];
    red[w][2][16 + Qr * 4 + g][lq] = o2B2[g];
    red[w][3][16 + Qr * 4 + g][lq] = o2B3[g];
  }
  __syncthreads();  // B5: red(u2) ready

  // ctx u2
  {
    const int qrow = tid >> 3;
    const int d0 = (tid & 7) * 8;
    const float invq = 1.0f / (reds[1][0][qrow] + reds[1][1][qrow] +
                               reds[1][2][qrow] + reds[1][3][qrow]);
    u16x4 cv0, cv1;
#pragma unroll
    for (int jj = 0; jj < 8; ++jj) {
      const int d = d0 + jj;
      const int db = d >> 4, dd = d & 15;
      float sum = red[0][db][qrow][dd] + red[1][db][qrow][dd] +
                  red[2][db][qrow][dd] + red[3][db][qrow][dd];
      if (jj < 4) cv0[jj] = f2bf(sum * invq);
      else        cv1[jj - 4] = f2bf(sum * invq);
    }
    unsigned short* cb =
        ctx + ((size_t)(b * 1024 + qA2 + qrow)) * 1024 + hd * 64 + d0;
    *(u16x4*)cb = cv0;
    *(u16x4*)(cb + 4) = cv1;
  }
#undef QKEXP
#undef STORE8
#undef PACK8
}

// ---------------------------------------------------------------- launch
extern "C" void kernel_launch(void* const* d_in, const int* in_sizes, int n_in,
                              void* d_out, int out_size, void* d_ws, size_t ws_size,
                              hipStream_t stream) {
  const float* hs = (const float*)d_in[0];
  const float* Wq = (const float*)d_in[1];
  const float* bq = (const float*)d_in[2];
  const float* Wk = (const float*)d_in[3];
  const float* bk = (const float*)d_in[4];
  const float* Wv = (const float*)d_in[5];
  const float* bv = (const float*)d_in[6];
  const float* Wo = (const float*)d_in[7];
  const float* bo = (const float*)d_in[8];
  const float* de = (const float*)d_in[9];

  float* out = (float*)d_out;
  float* probs = out + (size_t)4 * 1024 * 1024;

  char* ws = (char*)d_ws;
  unsigned short* Xb  = (unsigned short*)(ws);                      // -> ctx later
  unsigned short* Wqb = (unsigned short*)(ws + ((size_t)8 << 20));
  unsigned short* Wkb = (unsigned short*)(ws + ((size_t)10 << 20));
  unsigned short* Wvb = (unsigned short*)(ws + ((size_t)12 << 20));
  unsigned short* Wob = (unsigned short*)(ws + ((size_t)14 << 20));
  unsigned short* Qb  = (unsigned short*)(ws + ((size_t)16 << 20));
  unsigned short* Kb  = (unsigned short*)(ws + ((size_t)24 << 20));
  unsigned short* Vt  = (unsigned short*)(ws + ((size_t)32 << 20));
  unsigned short* Db  = (unsigned short*)(ws + ((size_t)40 << 20));
  unsigned short* Cx  = Xb;   // ctx (after QKV gemm; X dead)

  cvt_f32_bf16<<<dim3(1024), dim3(256), 0, stream>>>(hs, Xb, (4 * 1024 * 1024) / 4);
  cvt_w4d<<<dim3(1025), dim3(256), 0, stream>>>(Wq, Wk, Wv, Wo, de,
                                                Wqb, Wkb, Wvb, Wob, Db);

  gemm_qkv3<<<dim3(768), dim3(256), 0, stream>>>(Xb, Wqb, Wkb, Wvb, bq, bk, bv,
                                                 Qb, Kb, Vt);

  attn_kernel<<<dim3(1024), dim3(256), 0, stream>>>(Qb, Kb, Vt, Db, probs, Cx);

  gemm_nt_f32<<<dim3(32, 8), dim3(256), 0, stream>>>(Cx, Wob, bo, out);
}

// Round 15
// 173.414 us; speedup vs baseline: 1.1553x; 1.1553x over previous
//
#include <hip/hip_runtime.h>

// Wav2Vec2BertSelfAttention on MI355X (gfx950)
// B=4, S=1024, HID=1024, NH=16, HD=64, LEFT=64, RIGHT=8, NUM_POS=73
//
// FINAL (= round 13, best measured: 173.8us):
//   1. cvt X f32->bf16; cvt_w4d: 4 weights + dist_emb in one launch
//   2. gemm_qkv3: fused [Q|K|V], outputs written directly in MFMA-fragment-
//      tiled per-(b,head) layouts so every attn load is a dense 1KB wave load
//   3. attn: block = (b,h,32 q-rows as 2 groups), 4 waves split k-cols.
//      PHASE-SPLIT: loop1 = K-load/QK/exp2/pack(paf regs);
//      loop2 = V-load/PV + fused normalized probs f32x4 stores.
//      Swapped+permuted QK makes score regs == PV A-fragment (no LDS P).
//   4. gemm_nt_f32: out = ctx @ Wo^T + bo
//   Q''[qt][dcg][lq][dc2][8]  K''[kt][half][dcg][p][dc2][8]
//   V''[vt2][db][lq][Qr][8]  (per (b,head) 128KB blocks)

using short8 = __attribute__((ext_vector_type(8))) short;
using f32x4  = __attribute__((ext_vector_type(4))) float;
using fl4    = __attribute__((ext_vector_type(4))) float;
using u16x4  = __attribute__((ext_vector_type(4))) unsigned short;

#define MFMA16(a, b, c) __builtin_amdgcn_mfma_f32_16x16x32_bf16((a), (b), (c), 0, 0, 0)

// 0.125 (1/sqrt(64)) * log2(e)
#define SCL2E 0.18033688011112042f

__device__ __forceinline__ float bf2f(unsigned short u) {
  union { unsigned int i; float f; } c;
  c.i = ((unsigned int)u) << 16;
  return c.f;
}
__device__ __forceinline__ unsigned short f2bf(float f) {
  union { float f; unsigned int i; } c;
  c.f = f;
  unsigned int x = c.i;
  return (unsigned short)((x + 0x7fffu + ((x >> 16) & 1u)) >> 16);  // RNE
}
__device__ __forceinline__ float u2f(unsigned u) {
  union { unsigned i; float f; } c;
  c.i = u;
  return c.f;
}

__device__ __forceinline__ void gload_lds16(const void* g, void* l) {
  __builtin_amdgcn_global_load_lds(
      (const __attribute__((address_space(1))) void*)g,
      (__attribute__((address_space(3))) void*)l, 16, 0, 0);
}

// ---------------------------------------------------------------- convert
__global__ void cvt_f32_bf16(const float* __restrict__ in,
                             unsigned short* __restrict__ out, int n4) {
  int i = blockIdx.x * blockDim.x + threadIdx.x;
  int stride = gridDim.x * blockDim.x;
  for (; i < n4; i += stride) {
    fl4 v = ((const fl4*)in)[i];
    u16x4 o;
    o[0] = f2bf(v[0]); o[1] = f2bf(v[1]); o[2] = f2bf(v[2]); o[3] = f2bf(v[3]);
    ((u16x4*)out)[i] = o;
  }
}

// 4 weight matrices -> bf16 + dist_emb -> padded bf16 [80][64], one launch.
__global__ void cvt_w4d(const float* __restrict__ w0, const float* __restrict__ w1,
                        const float* __restrict__ w2, const float* __restrict__ w3,
                        const float* __restrict__ de,
                        unsigned short* __restrict__ o0, unsigned short* __restrict__ o1,
                        unsigned short* __restrict__ o2, unsigned short* __restrict__ o3,
                        unsigned short* __restrict__ od) {
  if (blockIdx.x == 1024) {
    for (int i = threadIdx.x; i < 80 * 64; i += 256)
      od[i] = (i < 73 * 64) ? f2bf(de[i]) : (unsigned short)0;
    return;
  }
  const int which = blockIdx.x >> 8;
  const float* in = which == 0 ? w0 : which == 1 ? w1 : which == 2 ? w2 : w3;
  unsigned short* out = which == 0 ? o0 : which == 1 ? o1 : which == 2 ? o2 : o3;
  int i = (blockIdx.x & 255) * 256 + threadIdx.x;
#pragma unroll
  for (int it = 0; it < 4; ++it, i += 65536) {
    fl4 v = ((const fl4*)in)[i];
    u16x4 o;
    o[0] = f2bf(v[0]); o[1] = f2bf(v[1]); o[2] = f2bf(v[2]); o[3] = f2bf(v[3]);
    ((u16x4*)out)[i] = o;
  }
}

// ---------------------------------------------------------------- fused QKV GEMM
// r=0 Q = X@Wq^T (+bq), r=1 K = X@Wk^T (+bk), r=2 V = Wv@X^T (+bv, row)
// outputs written in attn-fragment-tiled per-(b,head) layouts.
__global__ __launch_bounds__(256)
void gemm_qkv3(const unsigned short* __restrict__ X,
               const unsigned short* __restrict__ Bq,
               const unsigned short* __restrict__ Bk,
               const unsigned short* __restrict__ Bv,
               const float* __restrict__ biq, const float* __restrict__ bik,
               const float* __restrict__ biv,
               unsigned short* __restrict__ Cq, unsigned short* __restrict__ Ck,
               unsigned short* __restrict__ Cv) {
  __shared__ unsigned short lA[128 * 32];
  __shared__ unsigned short lB[128 * 32];
  const int i = blockIdx.x;
  const int wgid = (i & 7) * 96 + (i >> 3);   // XCD-chunked (768 % 8 == 0)
  const int r = wgid >> 8;
  const int id = wgid & 255;
  int bm, bn;
  const unsigned short *Aa, *Bb;
  if (r == 2) {           // V: A=Wv rows (o=dglob), B=X rows (s-global)
    bm = (id >> 5) * 128; bn = (id & 31) * 128;
    Aa = Bv; Bb = X;
  } else {                // Q/K: A=X rows (s-global), B=W rows (dglob)
    bm = (id >> 3) * 128; bn = (id & 7) * 128;
    Aa = X; Bb = (r == 0) ? Bq : Bk;
  }
  const float* bias = (r == 0) ? biq : (r == 1) ? bik : biv;

  const int tid = threadIdx.x;
  const int wave = tid >> 6, lane = tid & 63;
  const int wm = wave >> 1, wn = wave & 1;

  f32x4 acc[4][4];
#pragma unroll
  for (int m = 0; m < 4; ++m)
#pragma unroll
    for (int n = 0; n < 4; ++n) acc[m][n] = (f32x4){0.f, 0.f, 0.f, 0.f};

  const int t0 = tid, t1 = tid + 256;
  const int ar0 = t0 >> 2, ak0 = (t0 & 3) * 8;
  const int ar1 = t1 >> 2, ak1 = (t1 & 3) * 8;
  const unsigned short* Ab = Aa + (size_t)bm * 1024;
  const unsigned short* Bbb = Bb + (size_t)bn * 1024;
  const int fr = lane & 15, fk = (lane >> 4) * 8;

  for (int kt = 0; kt < 1024; kt += 32) {
    gload_lds16(Ab + (size_t)ar0 * 1024 + kt + ak0, (void*)&lA[(wave * 64) * 8]);
    gload_lds16(Ab + (size_t)ar1 * 1024 + kt + ak1, (void*)&lA[2048 + (wave * 64) * 8]);
    gload_lds16(Bbb + (size_t)ar0 * 1024 + kt + ak0, (void*)&lB[(wave * 64) * 8]);
    gload_lds16(Bbb + (size_t)ar1 * 1024 + kt + ak1, (void*)&lB[2048 + (wave * 64) * 8]);
    __syncthreads();
    short8 af[4], bf[4];
#pragma unroll
    for (int m = 0; m < 4; ++m)
      af[m] = *(const short8*)&lA[(wm * 64 + m * 16 + fr) * 32 + fk];
#pragma unroll
    for (int n = 0; n < 4; ++n)
      bf[n] = *(const short8*)&lB[(wn * 64 + n * 16 + fr) * 32 + fk];
#pragma unroll
    for (int m = 0; m < 4; ++m)
#pragma unroll
      for (int n = 0; n < 4; ++n) acc[m][n] = MFMA16(af[m], bf[n], acc[m][n]);
    __syncthreads();
  }

  const int cr = (lane >> 4) * 4, cc = lane & 15;
#pragma unroll
  for (int m = 0; m < 4; ++m)
#pragma unroll
    for (int n = 0; n < 4; ++n) {
      const int col = bn + wn * 64 + n * 16 + cc;
#pragma unroll
      for (int g = 0; g < 4; ++g) {
        const int row = bm + wm * 64 + m * 16 + cr + g;
        if (r == 2) {
          // V: row = dglob, col = s-global
          const float v = acc[m][n][g] + bias[row];
          const int head = row >> 6, d = row & 63;
          const int b2 = col >> 10, sl = col & 1023, kk = sl & 31;
          size_t idx = ((size_t)((b2 << 4) + head) << 16) +
                       (size_t)(((sl >> 5) * 4 + (d >> 4)) * 512) +
                       (d & 15) * 32 + ((kk >> 3) * 8) + (kk & 7);
          Cv[idx] = f2bf(v);
        } else {
          // Q/K: row = s-global, col = dglob
          const float v = acc[m][n][g] + bias[col];
          const int head = col >> 6, d = col & 63;
          const int b2 = row >> 10, sl = row & 1023;
          const int dc = d >> 3;
          const size_t hb = (size_t)((b2 << 4) + head) << 16;
          if (r == 0) {
            size_t idx = hb +
                         (size_t)((((sl >> 4) * 2 + (dc >> 2)) * 16 + (sl & 15)) * 32) +
                         (dc & 3) * 8 + (d & 7);
            Cq[idx] = f2bf(v);
          } else {
            const int kt2 = sl >> 5;
            const int p = ((sl >> 3) & 3) * 4 + (sl & 3);
            const int half = (sl >> 2) & 1;
            size_t idx = hb +
                         (size_t)((((kt2 * 2 + half) * 2 + (dc >> 2)) * 512)) +
                         p * 32 + (dc & 3) * 8 + (d & 7);
            Ck[idx] = f2bf(v);
          }
        }
      }
    }
}

// ---------------------------------------------------------------- GEMM f32 out
__global__ __launch_bounds__(256)
void gemm_nt_f32(const unsigned short* __restrict__ A,
                 const unsigned short* __restrict__ B,
                 const float* __restrict__ bias, float* __restrict__ Cp) {
  __shared__ unsigned short lA[128 * 32];
  __shared__ unsigned short lB[128 * 32];
  const int tid = threadIdx.x;
  const int wave = tid >> 6, lane = tid & 63;
  const int wm = wave >> 1, wn = wave & 1;
  const int bm = blockIdx.x * 128, bn = blockIdx.y * 128;

  f32x4 acc[4][4];
#pragma unroll
  for (int m = 0; m < 4; ++m)
#pragma unroll
    for (int n = 0; n < 4; ++n) acc[m][n] = (f32x4){0.f, 0.f, 0.f, 0.f};

  const int t0 = tid, t1 = tid + 256;
  const int ar0 = t0 >> 2, ak0 = (t0 & 3) * 8;
  const int ar1 = t1 >> 2, ak1 = (t1 & 3) * 8;
  const unsigned short* Ab = A + (size_t)bm * 1024;
  const unsigned short* Bb = B + (size_t)bn * 1024;
  const int fr = lane & 15, fk = (lane >> 4) * 8;

  for (int kt = 0; kt < 1024; kt += 32) {
    gload_lds16(Ab + (size_t)ar0 * 1024 + kt + ak0, (void*)&lA[(wave * 64) * 8]);
    gload_lds16(Ab + (size_t)ar1 * 1024 + kt + ak1, (void*)&lA[2048 + (wave * 64) * 8]);
    gload_lds16(Bb + (size_t)ar0 * 1024 + kt + ak0, (void*)&lB[(wave * 64) * 8]);
    gload_lds16(Bb + (size_t)ar1 * 1024 + kt + ak1, (void*)&lB[2048 + (wave * 64) * 8]);
    __syncthreads();
    short8 af[4], bf[4];
#pragma unroll
    for (int m = 0; m < 4; ++m)
      af[m] = *(const short8*)&lA[(wm * 64 + m * 16 + fr) * 32 + fk];
#pragma unroll
    for (int n = 0; n < 4; ++n)
      bf[n] = *(const short8*)&lB[(wn * 64 + n * 16 + fr) * 32 + fk];
#pragma unroll
    for (int m = 0; m < 4; ++m)
#pragma unroll
      for (int n = 0; n < 4; ++n) acc[m][n] = MFMA16(af[m], bf[n], acc[m][n]);
    __syncthreads();
  }

  const int cr = (lane >> 4) * 4, cc = lane & 15;
#pragma unroll
  for (int m = 0; m < 4; ++m)
#pragma unroll
    for (int n = 0; n < 4; ++n) {
      const int col = bn + wn * 64 + n * 16 + cc;
#pragma unroll
      for (int g = 0; g < 4; ++g) {
        const int row = bm + wm * 64 + m * 16 + cr + g;
        Cp[(size_t)row * 1024 + col] = acc[m][n][g] + bias[col];
      }
    }
}

// ---------------------------------------------------------------- attention
// Block = (b,h, 32 q-rows = groups A,B of 16). 4 waves split k (256 cols).
// PHASE-SPLIT: loop1 K/QK/exp/pack -> paf regs; barrier (reds); loop2 V/PV +
// fused normalized probs stores; barrier (red); ctx reduce.
__global__ __launch_bounds__(256, 2)
void attn_kernel(const unsigned short* __restrict__ q,
                 const unsigned short* __restrict__ k,
                 const unsigned short* __restrict__ vt,
                 const unsigned short* __restrict__ demb_bf,
                 float* __restrict__ probs,
                 unsigned short* __restrict__ ctx) {
  const int i = blockIdx.x;
  const int x = i & 7, s = i >> 3;            // 2048 blocks, 2048%8==0
  const int bh = ((s >> 5) << 3) + x;         // 32 same-XCD blocks share bh
  const int qseg = s & 31;
  const int hd = bh & 15, b = bh >> 4;
  const int tid = threadIdx.x, w = tid >> 6, lane = tid & 63;
  const int lq = lane & 15, Qr = lane >> 4;
  const int qA = qseg * 32, qB = qA + 16;

  __shared__ unsigned short qdc[32][78];   // bf16, PRE-SCALED by SCL2E
  __shared__ float reds[4][32];
  __shared__ float red[4][4][32][16];      // 32 KB partial PV

  const size_t hb = (size_t)((b << 4) + hd) << 16;  // per-(b,head) 64K u16 block
  const int lo16 = lq * 32 + Qr * 8;                // lane offset in 512-u16 block

  // Q frags (dense): Q''[qt][dcg][lq][dc2][8]
  const unsigned short* qh = q + hb + (size_t)(qseg * 4) * 512;
  short8 bqA0 = *(const short8*)(qh + lo16);
  short8 bqA1 = *(const short8*)(qh + 512 + lo16);
  short8 bqB0 = *(const short8*)(qh + 1024 + lo16);
  short8 bqB1 = *(const short8*)(qh + 1536 + lo16);

  // qd[q][p] = (Q[q] . dist_emb[p]) * SCL2E
  for (int pgq = w; pgq < 10; pgq += 4) {
    const int qblk = pgq >= 5;
    const int pg = qblk ? pgq - 5 : pgq;
    const unsigned short* dp = demb_bf + (size_t)(pg * 16 + lq) * 64 + Qr * 8;
    short8 a0 = *(const short8*)dp;
    short8 a1 = *(const short8*)(dp + 32);
    f32x4 c = (f32x4){0.f, 0.f, 0.f, 0.f};
    c = MFMA16(a0, qblk ? bqB0 : bqA0, c);
    c = MFMA16(a1, qblk ? bqB1 : bqA1, c);
#pragma unroll
    for (int g = 0; g < 4; ++g) {
      const int p = pg * 16 + Qr * 4 + g;
      if (p < 73) qdc[qblk * 16 + lq][p] = f2bf(c[g] * SCL2E);
    }
  }
  __syncthreads();

  const float qd0A = bf2f(qdc[lq][0]),       qd72A = bf2f(qdc[lq][72]);
  const float qd0B = bf2f(qdc[16 + lq][0]),  qd72B = bf2f(qdc[16 + lq][72]);

  float ssumA = 0.f, ssumB = 0.f;
  unsigned pafA[8][4], pafB[8][4];

  const unsigned short* kh = k + hb + (size_t)(w * 8) * 2048 + lo16;
  const unsigned short* vh = vt + hb + (size_t)(w * 8) * 2048 + lo16;

  // ---------------- phase 1: K loads + QK + exp + pack (independent iters)
#pragma unroll
  for (int t = 0; t < 8; ++t) {
    const unsigned short* kp = kh + t * 2048;
    short8 ae0 = *(const short8*)kp;
    short8 ae1 = *(const short8*)(kp + 512);
    short8 ao0 = *(const short8*)(kp + 1024);
    short8 ao1 = *(const short8*)(kp + 1536);

    f32x4 seA = (f32x4){0.f, 0.f, 0.f, 0.f}, soA = seA, seB = seA, soB = seA;
    seA = MFMA16(ae0, bqA0, seA); seA = MFMA16(ae1, bqA1, seA);
    soA = MFMA16(ao0, bqA0, soA); soA = MFMA16(ao1, bqA1, soA);
    seB = MFMA16(ae0, bqB0, seB); seB = MFMA16(ae1, bqB1, seB);
    soB = MFMA16(ao0, bqB0, soB); soB = MFMA16(ao1, bqB1, soB);

    const int tglob = w * 8 + t;
    // ---- group A
    {
      float pe[4], po[4];
      if (tglob * 32 + 31 < qA - 64) {
#pragma unroll
        for (int g = 0; g < 4; ++g) {
          pe[g] = exp2f(fmaf(seA[g], SCL2E, qd0A));
          po[g] = exp2f(fmaf(soA[g], SCL2E, qd0A));
        }
      } else if (tglob * 32 > qA + 23) {
#pragma unroll
        for (int g = 0; g < 4; ++g) {
          pe[g] = exp2f(fmaf(seA[g], SCL2E, qd72A));
          po[g] = exp2f(fmaf(soA[g], SCL2E, qd72A));
        }
      } else {
        const int c0 = tglob * 32 + Qr * 8 - (qA + lq);
#pragma unroll
        for (int g = 0; g < 4; ++g) {
          int d0 = c0 + g;     d0 = d0 < -64 ? -64 : (d0 > 8 ? 8 : d0);
          int d1 = c0 + 4 + g; d1 = d1 < -64 ? -64 : (d1 > 8 ? 8 : d1);
          pe[g] = exp2f(fmaf(seA[g], SCL2E, bf2f(qdc[lq][d0 + 64])));
          po[g] = exp2f(fmaf(soA[g], SCL2E, bf2f(qdc[lq][d1 + 64])));
        }
      }
#pragma unroll
      for (int g = 0; g < 4; ++g) ssumA += pe[g] + po[g];
      asm("v_cvt_pk_bf16_f32 %0, %1, %2" : "=v"(pafA[t][0]) : "v"(pe[0]), "v"(pe[1]));
      asm("v_cvt_pk_bf16_f32 %0, %1, %2" : "=v"(pafA[t][1]) : "v"(pe[2]), "v"(pe[3]));
      asm("v_cvt_pk_bf16_f32 %0, %1, %2" : "=v"(pafA[t][2]) : "v"(po[0]), "v"(po[1]));
      asm("v_cvt_pk_bf16_f32 %0, %1, %2" : "=v"(pafA[t][3]) : "v"(po[2]), "v"(po[3]));
    }
    // ---- group B
    {
      float pe[4], po[4];
      if (tglob * 32 + 31 < qB - 64) {
#pragma unroll
        for (int g = 0; g < 4; ++g) {
          pe[g] = exp2f(fmaf(seB[g], SCL2E, qd0B));
          po[g] = exp2f(fmaf(soB[g], SCL2E, qd0B));
        }
      } else if (tglob * 32 > qB + 23) {
#pragma unroll
        for (int g = 0; g < 4; ++g) {
          pe[g] = exp2f(fmaf(seB[g], SCL2E, qd72B));
          po[g] = exp2f(fmaf(soB[g], SCL2E, qd72B));
        }
      } else {
        const int c0 = tglob * 32 + Qr * 8 - (qB + lq);
#pragma unroll
        for (int g = 0; g < 4; ++g) {
          int d0 = c0 + g;     d0 = d0 < -64 ? -64 : (d0 > 8 ? 8 : d0);
          int d1 = c0 + 4 + g; d1 = d1 < -64 ? -64 : (d1 > 8 ? 8 : d1);
          pe[g] = exp2f(fmaf(seB[g], SCL2E, bf2f(qdc[16 + lq][d0 + 64])));
          po[g] = exp2f(fmaf(soB[g], SCL2E, bf2f(qdc[16 + lq][d1 + 64])));
        }
      }
#pragma unroll
      for (int g = 0; g < 4; ++g) ssumB += pe[g] + po[g];
      asm("v_cvt_pk_bf16_f32 %0, %1, %2" : "=v"(pafB[t][0]) : "v"(pe[0]), "v"(pe[1]));
      asm("v_cvt_pk_bf16_f32 %0, %1, %2" : "=v"(pafB[t][1]) : "v"(pe[2]), "v"(pe[3]));
      asm("v_cvt_pk_bf16_f32 %0, %1, %2" : "=v"(pafB[t][2]) : "v"(po[0]), "v"(po[1]));
      asm("v_cvt_pk_bf16_f32 %0, %1, %2" : "=v"(pafB[t][3]) : "v"(po[2]), "v"(po[3]));
    }
  }
  ssumA += __shfl_xor(ssumA, 16, 64);
  ssumA += __shfl_xor(ssumA, 32, 64);
  ssumB += __shfl_xor(ssumB, 16, 64);
  ssumB += __shfl_xor(ssumB, 32, 64);
  if (lane < 16) {
    reds[w][lane] = ssumA;
    reds[w][16 + lane] = ssumB;
  }
  __syncthreads();  // reds ready -> normalization available in phase 2

  const float invA =
      1.0f / (reds[0][lq] + reds[1][lq] + reds[2][lq] + reds[3][lq]);
  const float invB = 1.0f / (reds[0][16 + lq] + reds[1][16 + lq] +
                             reds[2][16 + lq] + reds[3][16 + lq]);
  float* prowA = probs + ((size_t)bh * 1024 + qA + lq) * 1024 + w * 256 + Qr * 8;
  float* prowB = prowA + (size_t)16 * 1024;

  // ---------------- phase 2: V loads + PV + fused normalized probs stores
  f32x4 oA0 = (f32x4){0.f, 0.f, 0.f, 0.f}, oA1 = oA0, oA2 = oA0, oA3 = oA0;
  f32x4 oB0 = oA0, oB1 = oA0, oB2 = oA0, oB3 = oA0;
#pragma unroll
  for (int t = 0; t < 8; ++t) {
    const unsigned short* vp = vh + t * 2048;
    short8 v0 = *(const short8*)vp;
    short8 v1 = *(const short8*)(vp + 512);
    short8 v2 = *(const short8*)(vp + 1024);
    short8 v3 = *(const short8*)(vp + 1536);

    union { unsigned u[4]; short8 s8v; } ua, ub;
    ua.u[0] = pafA[t][0]; ua.u[1] = pafA[t][1];
    ua.u[2] = pafA[t][2]; ua.u[3] = pafA[t][3];
    ub.u[0] = pafB[t][0]; ub.u[1] = pafB[t][1];
    ub.u[2] = pafB[t][2]; ub.u[3] = pafB[t][3];
    const short8 pa = ua.s8v, pb = ub.s8v;
    oA0 = MFMA16(pa, v0, oA0);
    oA1 = MFMA16(pa, v1, oA1);
    oA2 = MFMA16(pa, v2, oA2);
    oA3 = MFMA16(pa, v3, oA3);
    oB0 = MFMA16(pb, v0, oB0);
    oB1 = MFMA16(pb, v1, oB1);
    oB2 = MFMA16(pb, v2, oB2);
    oB3 = MFMA16(pb, v3, oB3);

    f32x4 p0, p1;
    p0[0] = u2f(pafA[t][0] << 16) * invA;
    p0[1] = u2f(pafA[t][0] & 0xffff0000u) * invA;
    p0[2] = u2f(pafA[t][1] << 16) * invA;
    p0[3] = u2f(pafA[t][1] & 0xffff0000u) * invA;
    p1[0] = u2f(pafA[t][2] << 16) * invA;
    p1[1] = u2f(pafA[t][2] & 0xffff0000u) * invA;
    p1[2] = u2f(pafA[t][3] << 16) * invA;
    p1[3] = u2f(pafA[t][3] & 0xffff0000u) * invA;
    *(f32x4*)&prowA[t * 32] = p0;
    *(f32x4*)&prowA[t * 32 + 4] = p1;
    f32x4 q0, q1;
    q0[0] = u2f(pafB[t][0] << 16) * invB;
    q0[1] = u2f(pafB[t][0] & 0xffff0000u) * invB;
    q0[2] = u2f(pafB[t][1] << 16) * invB;
    q0[3] = u2f(pafB[t][1] & 0xffff0000u) * invB;
    q1[0] = u2f(pafB[t][2] << 16) * invB;
    q1[1] = u2f(pafB[t][2] & 0xffff0000u) * invB;
    q1[2] = u2f(pafB[t][3] << 16) * invB;
    q1[3] = u2f(pafB[t][3] & 0xffff0000u) * invB;
    *(f32x4*)&prowB[t * 32] = q0;
    *(f32x4*)&prowB[t * 32 + 4] = q1;
  }

  // partial PV -> LDS
#pragma unroll
  for (int g = 0; g < 4; ++g) {
    red[w][0][Qr * 4 + g][lq] = oA0[g];
    red[w][1][Qr * 4 + g][lq] = oA1[g];
    red[w][2][Qr * 4 + g][lq] = oA2[g];
    red[w][3][Qr * 4 + g][lq] = oA3[g];
    red[w][0][16 + Qr * 4 + g][lq] = oB0[g];
    red[w][1][16 + Qr * 4 + g][lq] = oB1[g];
    red[w][2][16 + Qr * 4 + g][lq] = oB2[g];
    red[w][3][16 + Qr * 4 + g][lq] = oB3[g];
  }
  __syncthreads();

  // ctx: thread -> q = tid>>3 (0..31), d = (tid&7)*8 + j
  {
    const int qrow = tid >> 3;
    const int d0 = (tid & 7) * 8;
    const float invq = 1.0f / (reds[0][qrow] + reds[1][qrow] +
                               reds[2][qrow] + reds[3][qrow]);
    u16x4 cv0, cv1;
#pragma unroll
    for (int j = 0; j < 8; ++j) {
      const int d = d0 + j;
      const int db = d >> 4, dd = d & 15;
      float sum = red[0][db][qrow][dd] + red[1][db][qrow][dd] +
                  red[2][db][qrow][dd] + red[3][db][qrow][dd];
      if (j < 4) cv0[j] = f2bf(sum * invq);
      else       cv1[j - 4] = f2bf(sum * invq);
    }
    unsigned short* cb =
        ctx + ((size_t)(b * 1024 + qA + qrow)) * 1024 + hd * 64 + d0;
    *(u16x4*)cb = cv0;
    *(u16x4*)(cb + 4) = cv1;
  }
}

// ---------------------------------------------------------------- launch
extern "C" void kernel_launch(void* const* d_in, const int* in_sizes, int n_in,
                              void* d_out, int out_size, void* d_ws, size_t ws_size,
                              hipStream_t stream) {
  const float* hs = (const float*)d_in[0];
  const float* Wq = (const float*)d_in[1];
  const float* bq = (const float*)d_in[2];
  const float* Wk = (const float*)d_in[3];
  const float* bk = (const float*)d_in[4];
  const float* Wv = (const float*)d_in[5];
  const float* bv = (const float*)d_in[6];
  const float* Wo = (const float*)d_in[7];
  const float* bo = (const float*)d_in[8];
  const float* de = (const float*)d_in[9];

  float* out = (float*)d_out;
  float* probs = out + (size_t)4 * 1024 * 1024;

  char* ws = (char*)d_ws;
  unsigned short* Xb  = (unsigned short*)(ws);                      // -> ctx later
  unsigned short* Wqb = (unsigned short*)(ws + ((size_t)8 << 20));
  unsigned short* Wkb = (unsigned short*)(ws + ((size_t)10 << 20));
  unsigned short* Wvb = (unsigned short*)(ws + ((size_t)12 << 20));
  unsigned short* Wob = (unsigned short*)(ws + ((size_t)14 << 20));
  unsigned short* Qb  = (unsigned short*)(ws + ((size_t)16 << 20));
  unsigned short* Kb  = (unsigned short*)(ws + ((size_t)24 << 20));
  unsigned short* Vt  = (unsigned short*)(ws + ((size_t)32 << 20));
  unsigned short* Db  = (unsigned short*)(ws + ((size_t)40 << 20));  // own slot
  unsigned short* Cx  = Xb;   // ctx (after QKV gemm; X dead)

  cvt_f32_bf16<<<dim3(1024), dim3(256), 0, stream>>>(hs, Xb, (4 * 1024 * 1024) / 4);
  cvt_w4d<<<dim3(1025), dim3(256), 0, stream>>>(Wq, Wk, Wv, Wo, de,
                                                Wqb, Wkb, Wvb, Wob, Db);

  gemm_qkv3<<<dim3(768), dim3(256), 0, stream>>>(Xb, Wqb, Wkb, Wvb, bq, bk, bv,
                                                 Qb, Kb, Vt);

  attn_kernel<<<dim3(2048), dim3(256), 0, stream>>>(Qb, Kb, Vt, Db, probs, Cx);

  gemm_nt_f32<<<dim3(32, 8), dim3(256), 0, stream>>>(Cx, Wob, bo, out);
}